// Round 12
// baseline (792.592 us; speedup 1.0000x reference)
//
#include <hip/hip_runtime.h>

static inline int div_up(int a, int b){ return (a + b - 1) / b; }

constexpr int FIN = 128;
constexpr unsigned long long DEG_MASK = ((unsigned long long)1 << 48) - 1;

// ---- CSR build ----------------------------------------------------------
// packed[d]: bits 48..63 = edge count, bits 0..47 = sum(w) in 16.32 fixed point.
// One returning 64-bit atomic per edge (device atomic floor ~23 G/s — measured:
// XCD-local copies do NOT help, r9). Launched in 4 sequential parts purely so
// the profiler's top-5 window (cutoff = slowest dispatch) exposes props/scatter.

__global__ __launch_bounds__(256) void count_deg_k(const int* __restrict__ dst,
    const float* __restrict__ w, unsigned long long* __restrict__ packed,
    unsigned short* __restrict__ ie, int e0, int e1)
{
    int e = e0 + blockIdx.x * 256 + threadIdx.x;
    if (e >= e1) return;
    int d = dst[e];
    unsigned long long add = ((unsigned long long)1 << 48)
                           | (unsigned long long)(w[e] * 4294967296.0f);
    unsigned long long old = atomicAdd(&packed[d], add);
    ie[e] = (unsigned short)(old >> 48);
}

__global__ __launch_bounds__(256) void scan_sum_k(const unsigned long long* __restrict__ packed,
    int* __restrict__ bsum, int n)
{
    __shared__ int lds[256];
    int t = threadIdx.x;
    int base = blockIdx.x * 1024 + t * 4;
    int s = 0;
    #pragma unroll
    for (int i = 0; i < 4; ++i) if (base + i < n) s += (int)(packed[base + i] >> 48);
    lds[t] = s; __syncthreads();
    for (int o = 128; o > 0; o >>= 1){
        if (t < o) lds[t] += lds[t + o];
        __syncthreads();
    }
    if (t == 0) bsum[blockIdx.x] = lds[0];
}

__global__ __launch_bounds__(256) void scan_block_k(int* __restrict__ bsum, int nb,
    int* __restrict__ rowptr, int n, int Etot)
{
    __shared__ int lds[256];
    int t = threadIdx.x;
    int v = (t < nb) ? bsum[t] : 0;
    lds[t] = v; __syncthreads();
    for (int o = 1; o < 256; o <<= 1){
        int add = (t >= o) ? lds[t - o] : 0;
        __syncthreads();
        lds[t] += add;
        __syncthreads();
    }
    if (t < nb) bsum[t] = lds[t] - v;   // exclusive
    if (t == 0) rowptr[n] = Etot;
}

__global__ __launch_bounds__(256) void scan_apply_k(const unsigned long long* __restrict__ packed,
    const int* __restrict__ bsum, int* __restrict__ rowptr, float* __restrict__ dis, int n)
{
    __shared__ int lds[256];
    int t = threadIdx.x;
    int base = blockIdx.x * 1024 + t * 4;
    int v[4]; int ts = 0;
    unsigned long long pk[4];
    #pragma unroll
    for (int i = 0; i < 4; ++i){
        pk[i] = (base + i < n) ? packed[base + i] : 0ull;
        v[i] = (int)(pk[i] >> 48); ts += v[i];
    }
    lds[t] = ts; __syncthreads();
    for (int o = 1; o < 256; o <<= 1){
        int add = (t >= o) ? lds[t - o] : 0;
        __syncthreads();
        lds[t] += add;
        __syncthreads();
    }
    int pre = lds[t] - ts + bsum[blockIdx.x];
    #pragma unroll
    for (int i = 0; i < 4; ++i){
        if (base + i < n){
            rowptr[base + i] = pre;
            float d = (float)(pk[i] & DEG_MASK) * (1.0f / 4294967296.0f);
            dis[base + i] = d > 0.f ? rsqrtf(d) : 0.f;
        }
        pre += v[i];
    }
}

// atomic-free scatter: pos = rowptr[d] + ie[e]
__global__ __launch_bounds__(256) void scatter_k(const int* __restrict__ src,
    const int* __restrict__ dst, const float* __restrict__ w,
    const float* __restrict__ dis, const int* __restrict__ rowptr,
    const unsigned short* __restrict__ ie, int2* __restrict__ edges, int E)
{
    int e = blockIdx.x * 256 + threadIdx.x;
    if (e >= E) return;
    int s = src[e], d = dst[e];
    float nm = dis[s] * w[e] * dis[d];
    int pos = rowptr[d] + (int)ie[e];
    edges[pos] = make_int2(s, __float_as_int(nm));
}

// ---- gemm1: z = x @ W1 into four [N][8] planes (k-major) ----------------

__global__ __launch_bounds__(256) void gemm1_k(const float* __restrict__ x,
    const float* __restrict__ W, float* __restrict__ z0, float* __restrict__ z1,
    float* __restrict__ z2, float* __restrict__ z3, int n)
{
    int node = blockIdx.x * 256 + threadIdx.x;
    if (node >= n) return;
    const float4* xr = (const float4*)(x + (size_t)node * FIN);
    float acc[32];
    #pragma unroll
    for (int o = 0; o < 32; ++o) acc[o] = 0.f;
    #pragma unroll 2
    for (int fc = 0; fc < FIN / 4; ++fc){
        float4 xv = xr[fc];
        #pragma unroll
        for (int jj = 0; jj < 4; ++jj){
            float xs = jj == 0 ? xv.x : jj == 1 ? xv.y : jj == 2 ? xv.z : xv.w;
            int f = fc * 4 + jj;
            #pragma unroll
            for (int k = 0; k < 4; ++k)
                #pragma unroll
                for (int h = 0; h < 8; ++h)
                    acc[k * 8 + h] = fmaf(xs, W[((size_t)(k * FIN + f)) * 8 + h], acc[k * 8 + h]);
        }
    }
    float* zp[4] = {z0, z1, z2, z3};
    #pragma unroll
    for (int k = 0; k < 4; ++k){
        float4* zr = (float4*)(zp[k] + (size_t)node * 8);
        zr[0] = make_float4(acc[k*8+0], acc[k*8+1], acc[k*8+2], acc[k*8+3]);
        zr[1] = make_float4(acc[k*8+4], acc[k*8+5], acc[k*8+6], acc[k*8+7]);
    }
}

// ---- small GEMM fallback (h[N][8] @ W -> 4 planes) ----------------------

__global__ __launch_bounds__(256) void gemm_small_k(const float* __restrict__ hin,
    const float* __restrict__ W, float* __restrict__ z0, float* __restrict__ z1,
    float* __restrict__ z2, float* __restrict__ z3, int n)
{
    int node = blockIdx.x * 256 + threadIdx.x;
    if (node >= n) return;
    const float4* hr = (const float4*)(hin + (size_t)node * 8);
    float4 p0 = hr[0], p1 = hr[1];
    float hv[8] = {p0.x, p0.y, p0.z, p0.w, p1.x, p1.y, p1.z, p1.w};
    float acc[32];
    #pragma unroll
    for (int o = 0; o < 32; ++o) acc[o] = 0.f;
    #pragma unroll
    for (int f = 0; f < 8; ++f)
        #pragma unroll
        for (int k = 0; k < 4; ++k)
            #pragma unroll
            for (int h = 0; h < 8; ++h)
                acc[k * 8 + h] = fmaf(hv[f], W[(k * 8 + f) * 8 + h], acc[k * 8 + h]);
    float* zp[4] = {z0, z1, z2, z3};
    #pragma unroll
    for (int k = 0; k < 4; ++k){
        float4* zr = (float4*)(zp[k] + (size_t)node * 8);
        zr[0] = make_float4(acc[k*8+0], acc[k*8+1], acc[k*8+2], acc[k*8+3]);
        zr[1] = make_float4(acc[k*8+4], acc[k*8+5], acc[k*8+6], acc[k*8+7]);
    }
}

// ---- propagation: uout[n] = addv[n] + sum_e norm * uin[src_e] -----------
// 8-lane group per node (lane = feature), 8-deep unrolled edge loop.
// [N][8] planes keep the gather working set at 3.2MB (per-XCD L2 resident).
// UNCHANGED from r9 for attribution; this round exposes its true cost in top-5.

template<bool RELU, bool GEMM>
__global__ __launch_bounds__(256) void prop_k(const int2* __restrict__ edges,
    const int* __restrict__ rowptr, const float* __restrict__ uin,
    const float* __restrict__ addv, const float* __restrict__ bias,
    float* __restrict__ uout, const float* __restrict__ Wn,
    float* __restrict__ zo0, float* __restrict__ zo1,
    float* __restrict__ zo2, float* __restrict__ zo3, int n)
{
    int t = blockIdx.x * 256 + threadIdx.x;
    int node = t >> 3, g = t & 7;
    if (node >= n) return;
    int r0 = rowptr[node], r1 = rowptr[node + 1];
    float acc = 0.f;
    int j = r0;
    for (; j + 8 <= r1; j += 8){
        int2 e0 = edges[j],   e1 = edges[j+1], e2 = edges[j+2], e3 = edges[j+3];
        int2 e4 = edges[j+4], e5 = edges[j+5], e6 = edges[j+6], e7 = edges[j+7];
        float a0 = uin[(size_t)e0.x * 8 + g];
        float a1 = uin[(size_t)e1.x * 8 + g];
        float a2 = uin[(size_t)e2.x * 8 + g];
        float a3 = uin[(size_t)e3.x * 8 + g];
        float a4 = uin[(size_t)e4.x * 8 + g];
        float a5 = uin[(size_t)e5.x * 8 + g];
        float a6 = uin[(size_t)e6.x * 8 + g];
        float a7 = uin[(size_t)e7.x * 8 + g];
        acc = fmaf(__int_as_float(e0.y), a0, acc);
        acc = fmaf(__int_as_float(e1.y), a1, acc);
        acc = fmaf(__int_as_float(e2.y), a2, acc);
        acc = fmaf(__int_as_float(e3.y), a3, acc);
        acc = fmaf(__int_as_float(e4.y), a4, acc);
        acc = fmaf(__int_as_float(e5.y), a5, acc);
        acc = fmaf(__int_as_float(e6.y), a6, acc);
        acc = fmaf(__int_as_float(e7.y), a7, acc);
    }
    for (; j < r1; ++j){
        int2 e0 = edges[j];
        acc = fmaf(__int_as_float(e0.y), uin[(size_t)e0.x * 8 + g], acc);
    }
    float v = addv[(size_t)node * 8 + g] + acc;
    if (RELU) v = fmaxf(v + bias[g], 0.f);
    uout[(size_t)node * 8 + g] = v;
    if (GEMM){
        int lane = threadIdx.x & 63;
        int gbase = lane & ~7;
        float hrow[8];
        #pragma unroll
        for (int f = 0; f < 8; ++f) hrow[f] = __shfl(v, gbase + f);
        // outputs o = g*4..g*4+3 all live in plane k = g>>1, h = (g&1)*4+q
        int k = g >> 1;
        float zv[4];
        #pragma unroll
        for (int q = 0; q < 4; ++q){
            int h = (g & 1) * 4 + q;
            float s = 0.f;
            #pragma unroll
            for (int f = 0; f < 8; ++f)
                s = fmaf(hrow[f], Wn[(k * 8 + f) * 8 + h], s);
            zv[q] = s;
        }
        float* zp = (k == 0) ? zo0 : (k == 1) ? zo1 : (k == 2) ? zo2 : zo3;
        *(float4*)(zp + (size_t)node * 8 + (g & 1) * 4) = make_float4(zv[0], zv[1], zv[2], zv[3]);
    }
}

// ---- pooling + FC -------------------------------------------------------

__global__ __launch_bounds__(256) void pool_k(const float* __restrict__ h1,
    const float* __restrict__ h2, const float* __restrict__ h3,
    const int* __restrict__ batch, unsigned* __restrict__ gmaxb,
    float* __restrict__ gsum, int* __restrict__ gcnt, int n)
{
    int t = blockIdx.x * 256 + threadIdx.x;
    int lane = threadIdx.x & 63;
    bool valid = (t < n);
    int b = valid ? batch[t] : -1;
    float v[24];
    #pragma unroll
    for (int q = 0; q < 24; ++q) v[q] = 0.f;
    if (valid){
        const float4* p1 = (const float4*)(h1 + (size_t)t * 8);
        const float4* p2 = (const float4*)(h2 + (size_t)t * 8);
        const float4* p3 = (const float4*)(h3 + (size_t)t * 8);
        float4 a0 = p1[0], a1 = p1[1], c0 = p2[0], c1 = p2[1], d0 = p3[0], d1 = p3[1];
        v[0]=a0.x; v[1]=a0.y; v[2]=a0.z; v[3]=a0.w; v[4]=a1.x; v[5]=a1.y; v[6]=a1.z; v[7]=a1.w;
        v[8]=c0.x; v[9]=c0.y; v[10]=c0.z; v[11]=c0.w; v[12]=c1.x; v[13]=c1.y; v[14]=c1.z; v[15]=c1.w;
        v[16]=d0.x; v[17]=d0.y; v[18]=d0.z; v[19]=d0.w; v[20]=d1.x; v[21]=d1.y; v[22]=d1.z; v[23]=d1.w;
    }
    int bl0 = __shfl(b, 0);
    bool uni = __all(b == bl0);
    if (uni){
        if (bl0 >= 0){
            #pragma unroll
            for (int q = 0; q < 24; ++q){
                float s = v[q], m = v[q];
                #pragma unroll
                for (int o = 1; o < 64; o <<= 1){
                    s += __shfl_xor(s, o);
                    m = fmaxf(m, __shfl_xor(m, o));
                }
                if (lane == 0){
                    atomicAdd(&gsum[bl0 * 24 + q], s);
                    atomicMax(&gmaxb[bl0 * 24 + q], __float_as_uint(m));  // vals >= 0: bit-monotone
                }
            }
            if (lane == 0) atomicAdd(&gcnt[bl0], 64);
        }
    } else if (valid){
        #pragma unroll
        for (int q = 0; q < 24; ++q){
            atomicAdd(&gsum[b * 24 + q], v[q]);
            atomicMax(&gmaxb[b * 24 + q], __float_as_uint(v[q]));
        }
        atomicAdd(&gcnt[b], 1);
    }
}

__global__ __launch_bounds__(64) void fc_k(const unsigned* __restrict__ gmaxb,
    const float* __restrict__ gsum, const int* __restrict__ gcnt,
    const float* __restrict__ fcW, const float* __restrict__ fcb,
    float* __restrict__ out, int G)
{
    int g = threadIdx.x;
    if (g >= G) return;
    float pooled[48];
    #pragma unroll
    for (int q = 0; q < 24; ++q) pooled[q] = __uint_as_float(gmaxb[g * 24 + q]);
    float c = (float)gcnt[g];
    if (c < 1.f) c = 1.f;
    float inv = 1.f / c;
    #pragma unroll
    for (int q = 0; q < 24; ++q) pooled[24 + q] = gsum[g * 24 + q] * inv;
    float o0 = fcb[0], o1 = fcb[1];
    #pragma unroll
    for (int j = 0; j < 48; ++j){
        o0 = fmaf(pooled[j], fcW[j * 2 + 0], o0);
        o1 = fmaf(pooled[j], fcW[j * 2 + 1], o1);
    }
    out[g * 2 + 0] = o0;
    out[g * 2 + 1] = o1;
}

// ---- launch -------------------------------------------------------------

extern "C" void kernel_launch(void* const* d_in, const int* in_sizes, int n_in,
                              void* d_out, int out_size, void* d_ws, size_t ws_size,
                              hipStream_t stream)
{
    const float* x    = (const float*)d_in[0];
    const int*   ei   = (const int*)d_in[1];
    const int*   batch= (const int*)d_in[2];
    const float* w    = (const float*)d_in[3];
    const float* W1   = (const float*)d_in[4];
    const float* b1   = (const float*)d_in[5];
    const float* W2   = (const float*)d_in[6];
    const float* b2   = (const float*)d_in[7];
    const float* W3   = (const float*)d_in[8];
    const float* b3   = (const float*)d_in[9];
    const float* fcW  = (const float*)d_in[10];
    const float* fcb  = (const float*)d_in[11];
    float* out = (float*)d_out;

    const int N = in_sizes[2];
    const int E = in_sizes[3];
    const int G = out_size / 2;
    const int* src = ei;
    const int* dst = ei + E;

    char* base = (char*)d_ws;
    size_t off = 0;
    auto alloc = [&](size_t bytes) -> char* {
        char* r = base + off;
        off += (bytes + 255) & ~(size_t)255;
        return r;
    };
    unsigned long long* packed = (unsigned long long*)alloc((size_t)N * 8);  // zeroed
    unsigned* gmaxb  = (unsigned*)alloc((size_t)G * 24 * 4);  // zeroed
    float*    gsum   = (float*)   alloc((size_t)G * 24 * 4);  // zeroed
    int*      gcnt   = (int*)     alloc((size_t)G * 4);       // zeroed
    size_t zero_bytes = off;
    float*    dis    = (float*)   alloc((size_t)N * 4);
    unsigned short* ie = (unsigned short*)alloc((size_t)E * 2);
    int*      rowptr = (int*)     alloc((size_t)(N + 1) * 4);
    int*      bsum   = (int*)     alloc(256 * 4);
    int2*     edges  = (int2*)    alloc((size_t)E * 8);
    float*    zA[4], *zB[4];
    for (int k = 0; k < 4; ++k) zA[k] = (float*)alloc((size_t)N * 8 * 4);
    float*    u0     = (float*)   alloc((size_t)N * 8 * 4);
    float*    u1     = (float*)   alloc((size_t)N * 8 * 4);
    float*    h1     = (float*)   alloc((size_t)N * 8 * 4);
    float*    h2     = (float*)   alloc((size_t)N * 8 * 4);
    float*    h3     = (float*)   alloc((size_t)N * 8 * 4);
    for (int k = 0; k < 4; ++k) zB[k] = (float*)alloc((size_t)N * 8 * 4);
    bool fused = (off <= ws_size);
    if (!fused) for (int k = 0; k < 4; ++k) zB[k] = zA[k];  // sequential fallback

    hipMemsetAsync(d_ws, 0, zero_bytes, stream);

    dim3 blk(256);
    // 4 sequential parts (diagnostic split — lowers top-5 cutoff to ~35us)
    int Q = div_up(E, 4 * 256) * 256;
    for (int p = 0; p < 4; ++p){
        int e0 = p * Q, e1 = min(E, (p + 1) * Q);
        if (e0 >= e1) break;
        count_deg_k<<<div_up(e1 - e0, 256), blk, 0, stream>>>(dst, w, packed, ie, e0, e1);
    }
    gemm1_k<<<div_up(N, 256), blk, 0, stream>>>(x, W1, zA[0], zA[1], zA[2], zA[3], N);
    int nb = div_up(N, 1024);
    scan_sum_k  <<<nb, blk, 0, stream>>>(packed, bsum, N);
    scan_block_k<<<1,  blk, 0, stream>>>(bsum, nb, rowptr, N, E);
    scan_apply_k<<<nb, blk, 0, stream>>>(packed, bsum, rowptr, dis, N);
    scatter_k<<<div_up(E, 256), blk, 0, stream>>>(src, dst, w, dis, rowptr, ie, edges, E);

    int pb = div_up(N * 8, 256);   // 8-lane group per node
    // layer 1: Horner z0 + T(z1 + T(z2 + T z3))
    prop_k<false,false><<<pb, blk, 0, stream>>>(edges, rowptr, zA[3], zA[2], nullptr, u0, nullptr, nullptr, nullptr, nullptr, nullptr, N);
    prop_k<false,false><<<pb, blk, 0, stream>>>(edges, rowptr, u0, zA[1], nullptr, u1, nullptr, nullptr, nullptr, nullptr, nullptr, N);
    if (fused){
        prop_k<true,true ><<<pb, blk, 0, stream>>>(edges, rowptr, u1, zA[0], b1, h1, W2, zB[0], zB[1], zB[2], zB[3], N);
    } else {
        prop_k<true,false><<<pb, blk, 0, stream>>>(edges, rowptr, u1, zA[0], b1, h1, nullptr, nullptr, nullptr, nullptr, nullptr, N);
        gemm_small_k<<<div_up(N, 256), blk, 0, stream>>>(h1, W2, zB[0], zB[1], zB[2], zB[3], N);
    }
    // layer 2
    prop_k<false,false><<<pb, blk, 0, stream>>>(edges, rowptr, zB[3], zB[2], nullptr, u0, nullptr, nullptr, nullptr, nullptr, nullptr, N);
    prop_k<false,false><<<pb, blk, 0, stream>>>(edges, rowptr, u0, zB[1], nullptr, u1, nullptr, nullptr, nullptr, nullptr, nullptr, N);
    if (fused){
        prop_k<true,true ><<<pb, blk, 0, stream>>>(edges, rowptr, u1, zB[0], b2, h2, W3, zA[0], zA[1], zA[2], zA[3], N);
    } else {
        prop_k<true,false><<<pb, blk, 0, stream>>>(edges, rowptr, u1, zB[0], b2, h2, nullptr, nullptr, nullptr, nullptr, nullptr, N);
        gemm_small_k<<<div_up(N, 256), blk, 0, stream>>>(h2, W3, zA[0], zA[1], zA[2], zA[3], N);
    }
    // layer 3
    prop_k<false,false><<<pb, blk, 0, stream>>>(edges, rowptr, zA[3], zA[2], nullptr, u0, nullptr, nullptr, nullptr, nullptr, nullptr, N);
    prop_k<false,false><<<pb, blk, 0, stream>>>(edges, rowptr, u0, zA[1], nullptr, u1, nullptr, nullptr, nullptr, nullptr, nullptr, N);
    prop_k<true,false><<<pb, blk, 0, stream>>>(edges, rowptr, u1, zA[0], b3, h3, nullptr, nullptr, nullptr, nullptr, nullptr, N);

    pool_k<<<div_up(N, 256), blk, 0, stream>>>(h1, h2, h3, batch, gmaxb, gsum, gcnt, N);
    fc_k<<<1, 64, 0, stream>>>(gmaxb, gsum, gcnt, fcW, fcb, out, G);
}

// Round 15
// 757.420 us; speedup vs baseline: 1.0464x; 1.0464x over previous
//
#include <hip/hip_runtime.h>

static inline int div_up(int a, int b){ return (a + b - 1) / b; }

constexpr int FIN = 128;
constexpr unsigned long long DEG_MASK = ((unsigned long long)1 << 48) - 1;

// ---- CSR build ----------------------------------------------------------
// packed[d]: bits 48..63 = edge count, bits 0..47 = sum(w) in 16.32 fixed point.
// One returning 64-bit atomic per edge (device atomic floor ~23 G/s; XCD-local
// copies don't help — r9). 4 sequential parts keep the profiler top-5 informative.
// Segments are PADDED TO EVEN length with {src=0, norm=0} dummies so prop can
// use 16B-aligned int4 record loads (2 records/load).

__global__ __launch_bounds__(256) void count_deg_k(const int* __restrict__ dst,
    const float* __restrict__ w, unsigned long long* __restrict__ packed,
    unsigned short* __restrict__ ie, int e0, int e1)
{
    int e = e0 + blockIdx.x * 256 + threadIdx.x;
    if (e >= e1) return;
    int d = dst[e];
    unsigned long long add = ((unsigned long long)1 << 48)
                           | (unsigned long long)(w[e] * 4294967296.0f);
    unsigned long long old = atomicAdd(&packed[d], add);
    ie[e] = (unsigned short)(old >> 48);
}

// sums PADDED counts ((cnt+1)&~1)
__global__ __launch_bounds__(256) void scan_sum_k(const unsigned long long* __restrict__ packed,
    int* __restrict__ bsum, int n)
{
    __shared__ int lds[256];
    int t = threadIdx.x;
    int base = blockIdx.x * 1024 + t * 4;
    int s = 0;
    #pragma unroll
    for (int i = 0; i < 4; ++i){
        if (base + i < n){
            int c = (int)(packed[base + i] >> 48);
            s += (c + 1) & ~1;
        }
    }
    lds[t] = s; __syncthreads();
    for (int o = 128; o > 0; o >>= 1){
        if (t < o) lds[t] += lds[t + o];
        __syncthreads();
    }
    if (t == 0) bsum[blockIdx.x] = lds[0];
}

__global__ __launch_bounds__(256) void scan_block_k(int* __restrict__ bsum, int nb,
    int* __restrict__ rowptr, int n)
{
    __shared__ int lds[256];
    int t = threadIdx.x;
    int v = (t < nb) ? bsum[t] : 0;
    lds[t] = v; __syncthreads();
    for (int o = 1; o < 256; o <<= 1){
        int add = (t >= o) ? lds[t - o] : 0;
        __syncthreads();
        lds[t] += add;
        __syncthreads();
    }
    if (t < nb) bsum[t] = lds[t] - v;          // exclusive
    if (t == nb - 1) rowptr[n] = lds[t];       // total padded count
}

// padded prefix -> rowptr; dis = rsqrt(deg); zero-fill the dummy slot of
// odd-degree nodes (dummies occupy slot rowptr[d]+cnt which scatter never touches).
__global__ __launch_bounds__(256) void scan_apply_k(const unsigned long long* __restrict__ packed,
    const int* __restrict__ bsum, int* __restrict__ rowptr, float* __restrict__ dis,
    int2* __restrict__ edges, int n)
{
    __shared__ int lds[256];
    int t = threadIdx.x;
    int base = blockIdx.x * 1024 + t * 4;
    int v[4]; int cr[4]; int ts = 0;
    unsigned long long pk[4];
    #pragma unroll
    for (int i = 0; i < 4; ++i){
        pk[i] = (base + i < n) ? packed[base + i] : 0ull;
        cr[i] = (int)(pk[i] >> 48);
        v[i] = (cr[i] + 1) & ~1;   // padded
        ts += v[i];
    }
    lds[t] = ts; __syncthreads();
    for (int o = 1; o < 256; o <<= 1){
        int add = (t >= o) ? lds[t - o] : 0;
        __syncthreads();
        lds[t] += add;
        __syncthreads();
    }
    int pre = lds[t] - ts + bsum[blockIdx.x];
    #pragma unroll
    for (int i = 0; i < 4; ++i){
        if (base + i < n){
            rowptr[base + i] = pre;
            float d = (float)(pk[i] & DEG_MASK) * (1.0f / 4294967296.0f);
            dis[base + i] = d > 0.f ? rsqrtf(d) : 0.f;
            if (cr[i] & 1) edges[pre + cr[i]] = make_int2(0, 0);  // dummy: 0*u[0]
        }
        pre += v[i];
    }
}

// atomic-free scatter: pos = rowptr[d] + ie[e]
__global__ __launch_bounds__(256) void scatter_k(const int* __restrict__ src,
    const int* __restrict__ dst, const float* __restrict__ w,
    const float* __restrict__ dis, const int* __restrict__ rowptr,
    const unsigned short* __restrict__ ie, int2* __restrict__ edges, int E)
{
    int e = blockIdx.x * 256 + threadIdx.x;
    if (e >= E) return;
    int s = src[e], d = dst[e];
    float nm = dis[s] * w[e] * dis[d];
    int pos = rowptr[d] + (int)ie[e];
    edges[pos] = make_int2(s, __float_as_int(nm));
}

// ---- gemm1: z = x @ W1 into four [N][8] planes (k-major) ----------------

__global__ __launch_bounds__(256) void gemm1_k(const float* __restrict__ x,
    const float* __restrict__ W, float* __restrict__ z0, float* __restrict__ z1,
    float* __restrict__ z2, float* __restrict__ z3, int n)
{
    int node = blockIdx.x * 256 + threadIdx.x;
    if (node >= n) return;
    const float4* xr = (const float4*)(x + (size_t)node * FIN);
    float acc[32];
    #pragma unroll
    for (int o = 0; o < 32; ++o) acc[o] = 0.f;
    #pragma unroll 2
    for (int fc = 0; fc < FIN / 4; ++fc){
        float4 xv = xr[fc];
        #pragma unroll
        for (int jj = 0; jj < 4; ++jj){
            float xs = jj == 0 ? xv.x : jj == 1 ? xv.y : jj == 2 ? xv.z : xv.w;
            int f = fc * 4 + jj;
            #pragma unroll
            for (int k = 0; k < 4; ++k)
                #pragma unroll
                for (int h = 0; h < 8; ++h)
                    acc[k * 8 + h] = fmaf(xs, W[((size_t)(k * FIN + f)) * 8 + h], acc[k * 8 + h]);
        }
    }
    float* zp[4] = {z0, z1, z2, z3};
    #pragma unroll
    for (int k = 0; k < 4; ++k){
        float4* zr = (float4*)(zp[k] + (size_t)node * 8);
        zr[0] = make_float4(acc[k*8+0], acc[k*8+1], acc[k*8+2], acc[k*8+3]);
        zr[1] = make_float4(acc[k*8+4], acc[k*8+5], acc[k*8+6], acc[k*8+7]);
    }
}

// ---- small GEMM fallback (h[N][8] @ W -> 4 planes) ----------------------

__global__ __launch_bounds__(256) void gemm_small_k(const float* __restrict__ hin,
    const float* __restrict__ W, float* __restrict__ z0, float* __restrict__ z1,
    float* __restrict__ z2, float* __restrict__ z3, int n)
{
    int node = blockIdx.x * 256 + threadIdx.x;
    if (node >= n) return;
    const float4* hr = (const float4*)(hin + (size_t)node * 8);
    float4 p0 = hr[0], p1 = hr[1];
    float hv[8] = {p0.x, p0.y, p0.z, p0.w, p1.x, p1.y, p1.z, p1.w};
    float acc[32];
    #pragma unroll
    for (int o = 0; o < 32; ++o) acc[o] = 0.f;
    #pragma unroll
    for (int f = 0; f < 8; ++f)
        #pragma unroll
        for (int k = 0; k < 4; ++k)
            #pragma unroll
            for (int h = 0; h < 8; ++h)
                acc[k * 8 + h] = fmaf(hv[f], W[(k * 8 + f) * 8 + h], acc[k * 8 + h]);
    float* zp[4] = {z0, z1, z2, z3};
    #pragma unroll
    for (int k = 0; k < 4; ++k){
        float4* zr = (float4*)(zp[k] + (size_t)node * 8);
        zr[0] = make_float4(acc[k*8+0], acc[k*8+1], acc[k*8+2], acc[k*8+3]);
        zr[1] = make_float4(acc[k*8+4], acc[k*8+5], acc[k*8+6], acc[k*8+7]);
    }
}

// ---- propagation: uout[n] = addv[n] + sum_e norm * uin[src_e] -----------
// 8-lane group per node (lane = feature). Segments padded even -> records
// loaded as int4 (2 records / 16B load): per 8 edges, 4 record loads + 8
// gathers (was 8+8). [N][8] planes keep gathers in per-XCD L2 (3.2MB).

template<bool RELU, bool GEMM>
__global__ __launch_bounds__(256) void prop_k(const int2* __restrict__ edges,
    const int* __restrict__ rowptr, const float* __restrict__ uin,
    const float* __restrict__ addv, const float* __restrict__ bias,
    float* __restrict__ uout, const float* __restrict__ Wn,
    float* __restrict__ zo0, float* __restrict__ zo1,
    float* __restrict__ zo2, float* __restrict__ zo3, int n)
{
    int t = blockIdx.x * 256 + threadIdx.x;
    int node = t >> 3, g = t & 7;
    if (node >= n) return;
    int r0 = rowptr[node], r1 = rowptr[node + 1];
    float acc = 0.f;
    int j = r0;
    for (; j + 8 <= r1; j += 8){
        int4 p0 = *(const int4*)(edges + j);
        int4 p1 = *(const int4*)(edges + j + 2);
        int4 p2 = *(const int4*)(edges + j + 4);
        int4 p3 = *(const int4*)(edges + j + 6);
        float a0 = uin[(size_t)p0.x * 8 + g];
        float a1 = uin[(size_t)p0.z * 8 + g];
        float a2 = uin[(size_t)p1.x * 8 + g];
        float a3 = uin[(size_t)p1.z * 8 + g];
        float a4 = uin[(size_t)p2.x * 8 + g];
        float a5 = uin[(size_t)p2.z * 8 + g];
        float a6 = uin[(size_t)p3.x * 8 + g];
        float a7 = uin[(size_t)p3.z * 8 + g];
        acc = fmaf(__int_as_float(p0.y), a0, acc);
        acc = fmaf(__int_as_float(p0.w), a1, acc);
        acc = fmaf(__int_as_float(p1.y), a2, acc);
        acc = fmaf(__int_as_float(p1.w), a3, acc);
        acc = fmaf(__int_as_float(p2.y), a4, acc);
        acc = fmaf(__int_as_float(p2.w), a5, acc);
        acc = fmaf(__int_as_float(p3.y), a6, acc);
        acc = fmaf(__int_as_float(p3.w), a7, acc);
    }
    for (; j < r1; j += 2){   // padded even: tail granularity 2, still int4
        int4 p0 = *(const int4*)(edges + j);
        acc = fmaf(__int_as_float(p0.y), uin[(size_t)p0.x * 8 + g], acc);
        acc = fmaf(__int_as_float(p0.w), uin[(size_t)p0.z * 8 + g], acc);
    }
    float v = addv[(size_t)node * 8 + g] + acc;
    if (RELU) v = fmaxf(v + bias[g], 0.f);
    uout[(size_t)node * 8 + g] = v;
    if (GEMM){
        int lane = threadIdx.x & 63;
        int gbase = lane & ~7;
        float hrow[8];
        #pragma unroll
        for (int f = 0; f < 8; ++f) hrow[f] = __shfl(v, gbase + f);
        // outputs o = g*4..g*4+3 all live in plane k = g>>1, h = (g&1)*4+q
        int k = g >> 1;
        float zv[4];
        #pragma unroll
        for (int q = 0; q < 4; ++q){
            int h = (g & 1) * 4 + q;
            float s = 0.f;
            #pragma unroll
            for (int f = 0; f < 8; ++f)
                s = fmaf(hrow[f], Wn[(k * 8 + f) * 8 + h], s);
            zv[q] = s;
        }
        float* zp = (k == 0) ? zo0 : (k == 1) ? zo1 : (k == 2) ? zo2 : zo3;
        *(float4*)(zp + (size_t)node * 8 + (g & 1) * 4) = make_float4(zv[0], zv[1], zv[2], zv[3]);
    }
}

// ---- pooling + FC -------------------------------------------------------

__global__ __launch_bounds__(256) void pool_k(const float* __restrict__ h1,
    const float* __restrict__ h2, const float* __restrict__ h3,
    const int* __restrict__ batch, unsigned* __restrict__ gmaxb,
    float* __restrict__ gsum, int* __restrict__ gcnt, int n)
{
    int t = blockIdx.x * 256 + threadIdx.x;
    int lane = threadIdx.x & 63;
    bool valid = (t < n);
    int b = valid ? batch[t] : -1;
    float v[24];
    #pragma unroll
    for (int q = 0; q < 24; ++q) v[q] = 0.f;
    if (valid){
        const float4* p1 = (const float4*)(h1 + (size_t)t * 8);
        const float4* p2 = (const float4*)(h2 + (size_t)t * 8);
        const float4* p3 = (const float4*)(h3 + (size_t)t * 8);
        float4 a0 = p1[0], a1 = p1[1], c0 = p2[0], c1 = p2[1], d0 = p3[0], d1 = p3[1];
        v[0]=a0.x; v[1]=a0.y; v[2]=a0.z; v[3]=a0.w; v[4]=a1.x; v[5]=a1.y; v[6]=a1.z; v[7]=a1.w;
        v[8]=c0.x; v[9]=c0.y; v[10]=c0.z; v[11]=c0.w; v[12]=c1.x; v[13]=c1.y; v[14]=c1.z; v[15]=c1.w;
        v[16]=d0.x; v[17]=d0.y; v[18]=d0.z; v[19]=d0.w; v[20]=d1.x; v[21]=d1.y; v[22]=d1.z; v[23]=d1.w;
    }
    int bl0 = __shfl(b, 0);
    bool uni = __all(b == bl0);
    if (uni){
        if (bl0 >= 0){
            #pragma unroll
            for (int q = 0; q < 24; ++q){
                float s = v[q], m = v[q];
                #pragma unroll
                for (int o = 1; o < 64; o <<= 1){
                    s += __shfl_xor(s, o);
                    m = fmaxf(m, __shfl_xor(m, o));
                }
                if (lane == 0){
                    atomicAdd(&gsum[bl0 * 24 + q], s);
                    atomicMax(&gmaxb[bl0 * 24 + q], __float_as_uint(m));  // vals >= 0: bit-monotone
                }
            }
            if (lane == 0) atomicAdd(&gcnt[bl0], 64);
        }
    } else if (valid){
        #pragma unroll
        for (int q = 0; q < 24; ++q){
            atomicAdd(&gsum[b * 24 + q], v[q]);
            atomicMax(&gmaxb[b * 24 + q], __float_as_uint(v[q]));
        }
        atomicAdd(&gcnt[b], 1);
    }
}

__global__ __launch_bounds__(64) void fc_k(const unsigned* __restrict__ gmaxb,
    const float* __restrict__ gsum, const int* __restrict__ gcnt,
    const float* __restrict__ fcW, const float* __restrict__ fcb,
    float* __restrict__ out, int G)
{
    int g = threadIdx.x;
    if (g >= G) return;
    float pooled[48];
    #pragma unroll
    for (int q = 0; q < 24; ++q) pooled[q] = __uint_as_float(gmaxb[g * 24 + q]);
    float c = (float)gcnt[g];
    if (c < 1.f) c = 1.f;
    float inv = 1.f / c;
    #pragma unroll
    for (int q = 0; q < 24; ++q) pooled[24 + q] = gsum[g * 24 + q] * inv;
    float o0 = fcb[0], o1 = fcb[1];
    #pragma unroll
    for (int j = 0; j < 48; ++j){
        o0 = fmaf(pooled[j], fcW[j * 2 + 0], o0);
        o1 = fmaf(pooled[j], fcW[j * 2 + 1], o1);
    }
    out[g * 2 + 0] = o0;
    out[g * 2 + 1] = o1;
}

// ---- launch -------------------------------------------------------------

extern "C" void kernel_launch(void* const* d_in, const int* in_sizes, int n_in,
                              void* d_out, int out_size, void* d_ws, size_t ws_size,
                              hipStream_t stream)
{
    const float* x    = (const float*)d_in[0];
    const int*   ei   = (const int*)d_in[1];
    const int*   batch= (const int*)d_in[2];
    const float* w    = (const float*)d_in[3];
    const float* W1   = (const float*)d_in[4];
    const float* b1   = (const float*)d_in[5];
    const float* W2   = (const float*)d_in[6];
    const float* b2   = (const float*)d_in[7];
    const float* W3   = (const float*)d_in[8];
    const float* b3   = (const float*)d_in[9];
    const float* fcW  = (const float*)d_in[10];
    const float* fcb  = (const float*)d_in[11];
    float* out = (float*)d_out;

    const int N = in_sizes[2];
    const int E = in_sizes[3];
    const int G = out_size / 2;
    const int* src = ei;
    const int* dst = ei + E;

    char* base = (char*)d_ws;
    size_t off = 0;
    auto alloc = [&](size_t bytes) -> char* {
        char* r = base + off;
        off += (bytes + 255) & ~(size_t)255;
        return r;
    };
    unsigned long long* packed = (unsigned long long*)alloc((size_t)N * 8);  // zeroed
    unsigned* gmaxb  = (unsigned*)alloc((size_t)G * 24 * 4);  // zeroed
    float*    gsum   = (float*)   alloc((size_t)G * 24 * 4);  // zeroed
    int*      gcnt   = (int*)     alloc((size_t)G * 4);       // zeroed
    size_t zero_bytes = off;
    float*    dis    = (float*)   alloc((size_t)N * 4);
    unsigned short* ie = (unsigned short*)alloc((size_t)E * 2);
    int*      rowptr = (int*)     alloc((size_t)(N + 1) * 4);
    int*      bsum   = (int*)     alloc(256 * 4);
    int2*     edges  = (int2*)    alloc(((size_t)E + N) * 8);   // + padding slots
    float*    zA[4], *zB[4];
    for (int k = 0; k < 4; ++k) zA[k] = (float*)alloc((size_t)N * 8 * 4);
    float*    u0     = (float*)   alloc((size_t)N * 8 * 4);
    float*    u1     = (float*)   alloc((size_t)N * 8 * 4);
    float*    h1     = (float*)   alloc((size_t)N * 8 * 4);
    float*    h2     = (float*)   alloc((size_t)N * 8 * 4);
    float*    h3     = (float*)   alloc((size_t)N * 8 * 4);
    for (int k = 0; k < 4; ++k) zB[k] = (float*)alloc((size_t)N * 8 * 4);
    bool fused = (off <= ws_size);
    if (!fused) for (int k = 0; k < 4; ++k) zB[k] = zA[k];  // sequential fallback

    hipMemsetAsync(d_ws, 0, zero_bytes, stream);

    dim3 blk(256);
    // 4 sequential parts (keeps top-5 informative; same total atomic work)
    int Q = div_up(E, 4 * 256) * 256;
    for (int p = 0; p < 4; ++p){
        int e0 = p * Q, e1 = min(E, (p + 1) * Q);
        if (e0 >= e1) break;
        count_deg_k<<<div_up(e1 - e0, 256), blk, 0, stream>>>(dst, w, packed, ie, e0, e1);
    }
    gemm1_k<<<div_up(N, 256), blk, 0, stream>>>(x, W1, zA[0], zA[1], zA[2], zA[3], N);
    int nb = div_up(N, 1024);
    scan_sum_k  <<<nb, blk, 0, stream>>>(packed, bsum, N);
    scan_block_k<<<1,  blk, 0, stream>>>(bsum, nb, rowptr, N);
    scan_apply_k<<<nb, blk, 0, stream>>>(packed, bsum, rowptr, dis, edges, N);
    scatter_k<<<div_up(E, 256), blk, 0, stream>>>(src, dst, w, dis, rowptr, ie, edges, E);

    int pb = div_up(N * 8, 256);   // 8-lane group per node
    // layer 1: Horner z0 + T(z1 + T(z2 + T z3))
    prop_k<false,false><<<pb, blk, 0, stream>>>(edges, rowptr, zA[3], zA[2], nullptr, u0, nullptr, nullptr, nullptr, nullptr, nullptr, N);
    prop_k<false,false><<<pb, blk, 0, stream>>>(edges, rowptr, u0, zA[1], nullptr, u1, nullptr, nullptr, nullptr, nullptr, nullptr, N);
    if (fused){
        prop_k<true,true ><<<pb, blk, 0, stream>>>(edges, rowptr, u1, zA[0], b1, h1, W2, zB[0], zB[1], zB[2], zB[3], N);
    } else {
        prop_k<true,false><<<pb, blk, 0, stream>>>(edges, rowptr, u1, zA[0], b1, h1, nullptr, nullptr, nullptr, nullptr, nullptr, N);
        gemm_small_k<<<div_up(N, 256), blk, 0, stream>>>(h1, W2, zB[0], zB[1], zB[2], zB[3], N);
    }
    // layer 2
    prop_k<false,false><<<pb, blk, 0, stream>>>(edges, rowptr, zB[3], zB[2], nullptr, u0, nullptr, nullptr, nullptr, nullptr, nullptr, N);
    prop_k<false,false><<<pb, blk, 0, stream>>>(edges, rowptr, u0, zB[1], nullptr, u1, nullptr, nullptr, nullptr, nullptr, nullptr, N);
    if (fused){
        prop_k<true,true ><<<pb, blk, 0, stream>>>(edges, rowptr, u1, zB[0], b2, h2, W3, zA[0], zA[1], zA[2], zA[3], N);
    } else {
        prop_k<true,false><<<pb, blk, 0, stream>>>(edges, rowptr, u1, zB[0], b2, h2, nullptr, nullptr, nullptr, nullptr, nullptr, N);
        gemm_small_k<<<div_up(N, 256), blk, 0, stream>>>(h2, W3, zA[0], zA[1], zA[2], zA[3], N);
    }
    // layer 3
    prop_k<false,false><<<pb, blk, 0, stream>>>(edges, rowptr, zA[3], zA[2], nullptr, u0, nullptr, nullptr, nullptr, nullptr, nullptr, N);
    prop_k<false,false><<<pb, blk, 0, stream>>>(edges, rowptr, u0, zA[1], nullptr, u1, nullptr, nullptr, nullptr, nullptr, nullptr, N);
    prop_k<true,false><<<pb, blk, 0, stream>>>(edges, rowptr, u1, zA[0], b3, h3, nullptr, nullptr, nullptr, nullptr, nullptr, N);

    pool_k<<<div_up(N, 256), blk, 0, stream>>>(h1, h2, h3, batch, gmaxb, gsum, gcnt, N);
    fc_k<<<1, 64, 0, stream>>>(gmaxb, gsum, gcnt, fcW, fcb, out, G);
}